// Round 10
// baseline (228.980 us; speedup 1.0000x reference)
//
#include <hip/hip_runtime.h>
#include <hip/hip_bf16.h>
#include <math.h>

// Problem constants (fixed instance)
#define NTOK 2048
#define DIM 512
#define NCEN 500
#define NHEAD 8
#define HD 64
#define KWIN 128
#define DEPTH 8

typedef __attribute__((ext_vector_type(8))) short bf16x8;
typedef __attribute__((ext_vector_type(4))) float f32x4;

// ---------------- workspace layout (bytes) ----------------
// cen    f64 [512][512]     @ 0          (2 MB) row-major [c][d], rows>=500 zero
// codes  i32 [2048]         @ 2097152
// P      i32 [257]          @ 2105344
// bidx   i32 [2048]         @ 2106400
// pmax   f64 [16][2048]     @ 2115584    (256 KB)
// hist   i32 [8][256]       @ 2377728    (8 KB)   zeroed by centroids_k blk0
// qkv    f32 [2048][1536]   @ 3164160    (12 MB)
// Obuf   f32 [2048][512]    @ 15747072   (4 MB)   end 19941376 (proven-safe)

// ------------------------------------------------------------------
// K1: centroid means, row-major f64; also zeroes hist (block 0).
__global__ __launch_bounds__(256) void centroids_k(const float* __restrict__ p,
                                                   double* __restrict__ cen,
                                                   int* __restrict__ hist) {
    int c = blockIdx.x;
    if (c == 0) {
        for (int i = threadIdx.x; i < 8 * 256; i += 256) hist[i] = 0;
    }
    for (int d = threadIdx.x; d < DIM; d += 256) {
        double s = 0.0;
        if (c < NCEN) {
            const float* pc = p + (size_t)c * 5 * DIM;
            s  = (double)pc[0 * DIM + d];
            s += (double)pc[1 * DIM + d];
            s += (double)pc[2 * DIM + d];
            s += (double)pc[3 * DIM + d];
            s += (double)pc[4 * DIM + d];
            s = s / 5.0;
        }
        cen[(size_t)c * DIM + d] = s;
    }
}

// ------------------------------------------------------------------
// K2a: tiled f64 GEMM S = x * cen^T, fused max epilogue. 32-cen tiles:
// grid (16 ctiles, 32 ttiles) = 512 blocks (2/CU). Per-thread acc 4 tok x 2 cen.
// Same per-(t,c) k-accumulation order as 64-tile version -> bitwise-identical.
__global__ __launch_bounds__(256) void simsgemm_k(const float* __restrict__ x,
                                                  const double* __restrict__ cen,
                                                  double* __restrict__ pmax) {
    __shared__ double Xs[32][67];   // 17152 B
    __shared__ double Cs[32][35];   // 8960 B
    int tid = threadIdx.x;
    int c0 = blockIdx.x * 32;
    int t0 = blockIdx.y * 64;
    int tm = tid & 15, tn = tid >> 4;

    double acc[4][2] = {};
    for (int k0 = 0; k0 < DIM; k0 += 32) {
        // stage X: 64 tok x 32 k (f32 -> f64)
#pragma unroll
        for (int i = 0; i < 2; ++i) {
            int f = i * 256 + tid;
            int r = f >> 3, c4 = (f & 7) * 4;
            float4 va = *(const float4*)(x + (size_t)(t0 + r) * DIM + k0 + c4);
            Xs[c4 + 0][r] = (double)va.x; Xs[c4 + 1][r] = (double)va.y;
            Xs[c4 + 2][r] = (double)va.z; Xs[c4 + 3][r] = (double)va.w;
        }
        // stage C: 32 cen x 32 k (f64)
#pragma unroll
        for (int i = 0; i < 2; ++i) {
            int u = i * 256 + tid;
            int r = u >> 4, kk = (u & 15) * 2;
            double2 vc = *(const double2*)(cen + (size_t)(c0 + r) * DIM + k0 + kk);
            Cs[kk][r] = vc.x; Cs[kk + 1][r] = vc.y;
        }
        __syncthreads();
#pragma unroll 4
        for (int k = 0; k < 32; ++k) {
            double am[4], bn[2];
#pragma unroll
            for (int i = 0; i < 4; ++i) am[i] = Xs[k][tm + 16 * i];
#pragma unroll
            for (int j = 0; j < 2; ++j) bn[j] = Cs[k][tn + 16 * j];
#pragma unroll
            for (int i = 0; i < 4; ++i)
#pragma unroll
                for (int j = 0; j < 2; ++j) acc[i][j] += am[i] * bn[j];
        }
        __syncthreads();
    }

    double (*red)[67] = Xs;   // reuse (past last sync)
#pragma unroll
    for (int i = 0; i < 4; ++i) {
        double m = -1e300;
#pragma unroll
        for (int j = 0; j < 2; ++j) {
            bool valid = (c0 + tn + 16 * j) < NCEN;
            double v = valid ? acc[i][j] : -1e300;
            m = fmax(m, v);
        }
        red[tn][tm + 16 * i] = m;
    }
    __syncthreads();
    if (tid < 64) {
        double m = red[0][tid];
#pragma unroll
        for (int g = 1; g < 16; ++g) m = fmax(m, red[g][tid]);
        pmax[(size_t)blockIdx.x * NTOK + t0 + tid] = m;
    }
}

// ------------------------------------------------------------------
// K2b: merged norm + cantor codes + histogram atomics. One wave per token.
__global__ __launch_bounds__(256) void codes3_k(const float* __restrict__ x,
                                                const double* __restrict__ pmax,
                                                const float* __restrict__ gwp,
                                                int* __restrict__ codes,
                                                int* __restrict__ hist) {
    int tid = threadIdx.x;
    int lane = tid & 63;
    int w = tid >> 6;
    int n = blockIdx.x * 4 + w;

    const float* xr = x + (size_t)n * DIM;
    double ss = 0.0;
#pragma unroll
    for (int i = 0; i < 8; ++i) {
        double v = (double)xr[lane + i * 64];
        ss += v * v;
    }
#pragma unroll
    for (int m = 32; m; m >>= 1) ss += __shfl_xor(ss, m);

    // reduce pmax over 16 ctiles (lanes 0..15)
    double m = (lane < 16) ? pmax[(size_t)lane * NTOK + n] : -1e300;
    m = fmax(m, __shfl_xor(m, 8));
    m = fmax(m, __shfl_xor(m, 4));
    m = fmax(m, __shfl_xor(m, 2));
    m = fmax(m, __shfl_xor(m, 1));

    if (lane == 0) {
        double nrm = sqrt(ss) + 1e-12;
        double sims = m / nrm;
        double gwv = 1.0 / (1.0 + exp(-(double)gwp[0]));
        const double delta = 1.0 / 2047.0;
        double gd = 1.0 - sims;
        double pos = (n == NTOK - 1) ? 1.0 : (double)n * delta;
        double xc = pos * (1.0 - gwv) + gd * gwv;
        xc = fmin(fmax(xc, 1e-6), 1.0 - 1e-6);
        int code = 0;
#pragma unroll
        for (int l = 0; l < DEPTH; ++l) {
            double s3 = xc * 3.0;
            double dig = floor(s3);
            if (dig == 2.0) code |= 1 << (7 - l);
            xc = s3 - dig;
        }
        codes[n] = code;
        atomicAdd(&hist[(n >> 8) * 256 + code], 1);
    }
}

// ------------------------------------------------------------------
// K3: merged scan + stable scatter. 8 blocks x 256. Each block redundantly
// scans the 256-bucket totals, derives its own chunk offsets, scatters.
__global__ __launch_bounds__(256) void scanscatter_k(const int* __restrict__ hist,
                                                     const int* __restrict__ codes,
                                                     int* __restrict__ P,
                                                     int* __restrict__ bidx) {
    __shared__ int sc[256];
    __shared__ int cl[256];
    __shared__ int choff_l[256];
    int c = threadIdx.x;
    int b = blockIdx.x;
    int h[8];
    int t = 0;
#pragma unroll
    for (int g = 0; g < 8; ++g) { h[g] = hist[g * 256 + c]; t += h[g]; }
    sc[c] = t;
    __syncthreads();
    for (int off = 1; off < 256; off <<= 1) {
        int v = sc[c];
        int add = (c >= off) ? sc[c - off] : 0;
        __syncthreads();
        sc[c] = v + add;
        __syncthreads();
    }
    int incl = sc[c];
    int base = incl - t;
    if (b == 0) {
        P[c] = base;
        if (c == 255) P[256] = incl;   // == 2048
    }
    int pre = base;
    for (int g = 0; g < b; ++g) pre += h[g];
    choff_l[c] = pre;

    int idx = b * 256 + c;
    int myc = codes[idx];
    cl[c] = myc;
    __syncthreads();
    int rank = 0;
    for (int j = 0; j < c; ++j) rank += (cl[j] == myc) ? 1 : 0;
    bidx[choff_l[myc] + rank] = idx;
}

// ------------------------------------------------------------------
// K4: split-precision bf16x2 MFMA GEMM (proven R9). C = A*B^T + bias.
__global__ __launch_bounds__(256) void gemm_mfma_k(const float* __restrict__ A,
                                                   const float* __restrict__ Bw,
                                                   const float* __restrict__ bias,
                                                   float* __restrict__ Cc,
                                                   int Nn) {
    __shared__ ushort Ahi[64][40], Alo[64][40];
    __shared__ ushort Bhi[64][40], Blo[64][40];
    int tid = threadIdx.x;
    int lane = tid & 63;
    int w = tid >> 6;
    int n0 = blockIdx.x * 64;
    int m0 = blockIdx.y * 64;
    int r = tid >> 2, q = tid & 3;
    int l15 = lane & 15, l4 = lane >> 4;

    f32x4 acc[4];
#pragma unroll
    for (int nt = 0; nt < 4; ++nt) acc[nt] = (f32x4){0.f, 0.f, 0.f, 0.f};

    for (int k0 = 0; k0 < 512; k0 += 32) {
        {
            const float* src = A + (size_t)(m0 + r) * 512 + k0 + q * 8;
            ushort h8[8], l8[8];
#pragma unroll
            for (int e = 0; e < 8; ++e) {
                float v = src[e];
                __hip_bfloat16 hb = __float2bfloat16(v);
                float hf = __bfloat162float(hb);
                __hip_bfloat16 lb = __float2bfloat16(v - hf);
                h8[e] = *reinterpret_cast<ushort*>(&hb);
                l8[e] = *reinterpret_cast<ushort*>(&lb);
            }
            *(uint4*)&Ahi[r][q * 8] = *(uint4*)h8;
            *(uint4*)&Alo[r][q * 8] = *(uint4*)l8;
        }
        {
            const float* src = Bw + (size_t)(n0 + r) * 512 + k0 + q * 8;
            ushort h8[8], l8[8];
#pragma unroll
            for (int e = 0; e < 8; ++e) {
                float v = src[e];
                __hip_bfloat16 hb = __float2bfloat16(v);
                float hf = __bfloat162float(hb);
                __hip_bfloat16 lb = __float2bfloat16(v - hf);
                h8[e] = *reinterpret_cast<ushort*>(&hb);
                l8[e] = *reinterpret_cast<ushort*>(&lb);
            }
            *(uint4*)&Bhi[r][q * 8] = *(uint4*)h8;
            *(uint4*)&Blo[r][q * 8] = *(uint4*)l8;
        }
        __syncthreads();

        bf16x8 ah = *(const bf16x8*)&Ahi[w * 16 + l15][l4 * 8];
        bf16x8 al = *(const bf16x8*)&Alo[w * 16 + l15][l4 * 8];
#pragma unroll
        for (int nt = 0; nt < 4; ++nt) {
            bf16x8 bh = *(const bf16x8*)&Bhi[nt * 16 + l15][l4 * 8];
            bf16x8 bl = *(const bf16x8*)&Blo[nt * 16 + l15][l4 * 8];
            acc[nt] = __builtin_amdgcn_mfma_f32_16x16x32_bf16(ah, bh, acc[nt], 0, 0, 0);
            acc[nt] = __builtin_amdgcn_mfma_f32_16x16x32_bf16(ah, bl, acc[nt], 0, 0, 0);
            acc[nt] = __builtin_amdgcn_mfma_f32_16x16x32_bf16(al, bh, acc[nt], 0, 0, 0);
        }
        __syncthreads();
    }

#pragma unroll
    for (int nt = 0; nt < 4; ++nt) {
        int col = n0 + nt * 16 + l15;
        float bv = bias[col];
#pragma unroll
        for (int rr = 0; rr < 4; ++rr) {
            int row = m0 + w * 16 + l4 * 4 + rr;
            Cc[(size_t)row * Nn + col] = acc[nt][rr] + bv;
        }
    }
}

// ------------------------------------------------------------------
// K5: attention with fused route selection. 1 block = 1 query (Cantor order,
// XCD-chunked). Wave 0 computes the exact top-k route set (order-free) into
// LDS; then 4 waves do row-streaming scores/softmax/PV (proven attn_v3 body).
__global__ __launch_bounds__(256) void attn_v4(const float* __restrict__ qkv,
                                               const int* __restrict__ codes,
                                               const int* __restrict__ P,
                                               const int* __restrict__ bidx,
                                               float* __restrict__ Obuf) {
    __shared__ int rt[KWIN];
    __shared__ float sc[NHEAD][KWIN];
    __shared__ float part[4][DIM];
    int tid = threadIdx.x;
    int lane = tid & 63;
    int w = tid >> 6;

    int b = blockIdx.x;
    int ord = (b & 7) * 256 + (b >> 3);    // XCD-chunked, bijective on [0,2048)
    int q = bidx[ord];

    if (tid < 64) {
        int ci = codes[q];
        int dstar = -1;
        for (int r = 0; r < 4 && dstar < 0; ++r) {
            int d = r * 64 + lane;
            int loc = ci - d; if (loc < 0) loc = 0;
            int hic = ci + d; if (hic > 255) hic = 255;
            int cum = P[hic + 1] - P[loc];
            unsigned long long mb = __ballot(cum >= KWIN);
            if (mb) dstar = r * 64 + (int)__builtin_ctzll(mb);
        }
        int a = ci - dstar + 1; if (a < 0) a = 0;
        int bb = ci + dstar - 1; if (bb > 255) bb = 255;
        int inner = 0, baseA = 0;
        if (dstar > 0) { baseA = P[a]; inner = P[bb + 1] - baseA; }
        int rem = KWIN - inner;

        for (int t = lane; t < inner; t += 64) rt[t] = bidx[baseA + t];

        int lo = ci - dstar, hi = ci + dstar;
        int loS = 0, loL = 0, hiS = 0, hiL = 0;
        if (lo >= 0) { loS = P[lo]; loL = P[lo + 1] - loS; }
        if (dstar > 0 && hi <= 255) { hiS = P[hi]; hiL = P[hi + 1] - hiS; }

        int minI = rem - hiL; if (minI < 0) minI = 0;
        int maxI = (rem < loL) ? rem : loL;
        int ans = minI;
        int loI = minI, hiI = maxI;
        for (int it = 0; it < 12 && loI <= hiI; ++it) {
            int i = (loI + hiI) >> 1;
            int j = rem - i;
            bool tooMany = (i > 0 && j < hiL && bidx[loS + i - 1] > bidx[hiS + j]);
            bool tooFew  = (j > 0 && i < loL && bidx[hiS + j - 1] > bidx[loS + i]);
            if (tooMany) hiI = i - 1;
            else if (tooFew) loI = i + 1;
            else { ans = i; break; }
        }
        int ilo = ans;
        int jn = rem - ilo;
        for (int t = lane; t < ilo; t += 64) rt[inner + t] = bidx[loS + t];
        for (int t = lane; t < jn; t += 64) rt[inner + ilo + t] = bidx[hiS + t];
    }

    const float* qrow = qkv + (size_t)q * 1536 + lane * 8;
    float4 qa = *(const float4*)(qrow);
    float4 qb = *(const float4*)(qrow + 4);
    __syncthreads();

#pragma unroll 4
    for (int i = 0; i < 32; ++i) {
        int kk = w * 32 + i;
        int j = rt[kk];
        const float* kp = qkv + (size_t)j * 1536 + 512 + lane * 8;
        float4 k0 = *(const float4*)(kp);
        float4 k1 = *(const float4*)(kp + 4);
        float s = qa.x * k0.x + qa.y * k0.y + qa.z * k0.z + qa.w * k0.w
                + qb.x * k1.x + qb.y * k1.y + qb.z * k1.z + qb.w * k1.w;
        s += __shfl_xor(s, 1);
        s += __shfl_xor(s, 2);
        s += __shfl_xor(s, 4);
        if ((lane & 7) == 0) sc[lane >> 3][kk] = s * 0.125f;
    }
    __syncthreads();

    {
        int g = tid >> 5, l = tid & 31;
        float v0 = sc[g][l], v1 = sc[g][l + 32], v2 = sc[g][l + 64], v3 = sc[g][l + 96];
        float mx = fmaxf(fmaxf(v0, v1), fmaxf(v2, v3));
        for (int m = 16; m; m >>= 1) mx = fmaxf(mx, __shfl_xor(mx, m, 32));
        float e0 = expf(v0 - mx), e1 = expf(v1 - mx),
              e2 = expf(v2 - mx), e3 = expf(v3 - mx);
        float sum = e0 + e1 + e2 + e3;
        for (int m = 16; m; m >>= 1) sum += __shfl_xor(sum, m, 32);
        float inv = 1.f / sum;
        sc[g][l] = e0 * inv; sc[g][l + 32] = e1 * inv;
        sc[g][l + 64] = e2 * inv; sc[g][l + 96] = e3 * inv;
    }
    __syncthreads();

    float acc[8] = {0.f, 0.f, 0.f, 0.f, 0.f, 0.f, 0.f, 0.f};
    const float* sch = sc[lane >> 3];
#pragma unroll 4
    for (int i = 0; i < 32; ++i) {
        int kk = w * 32 + i;
        int j = rt[kk];
        float wgt = sch[kk];
        const float* vp = qkv + (size_t)j * 1536 + 1024 + lane * 8;
        float4 v0 = *(const float4*)(vp);
        float4 v1 = *(const float4*)(vp + 4);
        acc[0] += wgt * v0.x; acc[1] += wgt * v0.y;
        acc[2] += wgt * v0.z; acc[3] += wgt * v0.w;
        acc[4] += wgt * v1.x; acc[5] += wgt * v1.y;
        acc[6] += wgt * v1.z; acc[7] += wgt * v1.w;
    }
#pragma unroll
    for (int e = 0; e < 8; ++e) part[w][lane * 8 + e] = acc[e];
    __syncthreads();

#pragma unroll
    for (int r = 0; r < 2; ++r) {
        int d = r * 256 + tid;
        float o = part[0][d] + part[1][d] + part[2][d] + part[3][d];
        Obuf[(size_t)q * DIM + d] = o;
    }
}

// ------------------------------------------------------------------
extern "C" void kernel_launch(void* const* d_in, const int* in_sizes, int n_in,
                              void* d_out, int out_size, void* d_ws, size_t ws_size,
                              hipStream_t stream) {
    const float* x      = (const float*)d_in[0];
    const float* penta  = (const float*)d_in[1];
    const float* w_qkv  = (const float*)d_in[2];
    const float* b_qkv  = (const float*)d_in[3];
    const float* w_out  = (const float*)d_in[4];
    const float* b_out  = (const float*)d_in[5];
    const float* gw     = (const float*)d_in[6];
    float* out = (float*)d_out;
    char* ws = (char*)d_ws;

    double* cen   = (double*)(ws + 0);
    int* codes    = (int*)(ws + 2097152);
    int* P        = (int*)(ws + 2105344);
    int* bidx     = (int*)(ws + 2106400);
    double* pmax  = (double*)(ws + 2115584);   // [16][2048] f64, 256 KB
    int* hist     = (int*)(ws + 2377728);      // [8][256]
    float* qkv    = (float*)(ws + 3164160);
    float* Obuf   = (float*)(ws + 15747072);

    centroids_k<<<512, 256, 0, stream>>>(penta, cen, hist);
    simsgemm_k<<<dim3(16, 32), 256, 0, stream>>>(x, cen, pmax);
    codes3_k<<<512, 256, 0, stream>>>(x, pmax, gw, codes, hist);
    scanscatter_k<<<8, 256, 0, stream>>>(hist, codes, P, bidx);
    gemm_mfma_k<<<dim3(1536 / 64, 2048 / 64), 256, 0, stream>>>(x, w_qkv, b_qkv, qkv, 1536);
    attn_v4<<<NTOK, 256, 0, stream>>>(qkv, codes, P, bidx, Obuf);
    gemm_mfma_k<<<dim3(512 / 64, 2048 / 64), 256, 0, stream>>>(Obuf, w_out, b_out, out, 512);
}

// Round 11
// 220.172 us; speedup vs baseline: 1.0400x; 1.0400x over previous
//
#include <hip/hip_runtime.h>
#include <hip/hip_bf16.h>
#include <math.h>

// Problem constants (fixed instance)
#define NTOK 2048
#define DIM 512
#define NCEN 500
#define NHEAD 8
#define HD 64
#define KWIN 128
#define DEPTH 8

typedef __attribute__((ext_vector_type(8))) short bf16x8;
typedef __attribute__((ext_vector_type(4))) float f32x4;

// ---------------- workspace layout (bytes) ----------------
// cen    f64 [512][512]     @ 0          (2 MB) row-major [c][d], rows>=500 zero
// codes  i32 [2048]         @ 2097152
// P      i32 [257]          @ 2105344
// bidx   i32 [2048]         @ 2106400
// pmax   f64 [8][2048]      @ 2115584    (128 KB)
// hist   i32 [8][256]       @ 2377728    (8 KB)   zeroed by centroids_k blk0
// qkv    f32 [2048][1536]   @ 3164160    (12 MB)
// Obuf   f32 [2048][512]    @ 15747072   (4 MB)   end 19941376 (proven-safe)

// ------------------------------------------------------------------
// K1: centroid means, row-major f64; also zeroes hist (block 0).
__global__ __launch_bounds__(256) void centroids_k(const float* __restrict__ p,
                                                   double* __restrict__ cen,
                                                   int* __restrict__ hist) {
    int c = blockIdx.x;
    if (c == 0) {
        for (int i = threadIdx.x; i < 8 * 256; i += 256) hist[i] = 0;
    }
    for (int d = threadIdx.x; d < DIM; d += 256) {
        double s = 0.0;
        if (c < NCEN) {
            const float* pc = p + (size_t)c * 5 * DIM;
            s  = (double)pc[0 * DIM + d];
            s += (double)pc[1 * DIM + d];
            s += (double)pc[2 * DIM + d];
            s += (double)pc[3 * DIM + d];
            s += (double)pc[4 * DIM + d];
            s = s / 5.0;
        }
        cen[(size_t)c * DIM + d] = s;
    }
}

// ------------------------------------------------------------------
// K2a: tiled f64 GEMM S = x * cen^T, fused max epilogue (R9-proven exact
// configuration: 64x64 tile, 4x4 f64 fragments, grid (8,32); measured 54 us.
// R10's 32-cen variant measured 64 us — tile-space neighbor, rejected).
__global__ __launch_bounds__(256) void simsgemm_k(const float* __restrict__ x,
                                                  const double* __restrict__ cen,
                                                  double* __restrict__ pmax) {
    __shared__ double Xs[32][67];
    __shared__ double Cs[32][67];
    int tid = threadIdx.x;
    int c0 = blockIdx.x * 64;
    int t0 = blockIdx.y * 64;
    int tm = tid & 15, tn = tid >> 4;

    double acc[4][4] = {};
    for (int k0 = 0; k0 < DIM; k0 += 32) {
#pragma unroll
        for (int i = 0; i < 2; ++i) {
            int f = i * 256 + tid;
            int r = f >> 3, c4 = (f & 7) * 4;
            float4 va = *(const float4*)(x + (size_t)(t0 + r) * DIM + k0 + c4);
            Xs[c4 + 0][r] = (double)va.x; Xs[c4 + 1][r] = (double)va.y;
            Xs[c4 + 2][r] = (double)va.z; Xs[c4 + 3][r] = (double)va.w;
        }
#pragma unroll
        for (int i = 0; i < 4; ++i) {
            int u = i * 256 + tid;
            int r = u >> 4, kk = (u & 15) * 2;
            double2 vc = *(const double2*)(cen + (size_t)(c0 + r) * DIM + k0 + kk);
            Cs[kk][r] = vc.x; Cs[kk + 1][r] = vc.y;
        }
        __syncthreads();
#pragma unroll 4
        for (int k = 0; k < 32; ++k) {
            double am[4], bn[4];
#pragma unroll
            for (int i = 0; i < 4; ++i) am[i] = Xs[k][tm + 16 * i];
#pragma unroll
            for (int j = 0; j < 4; ++j) bn[j] = Cs[k][tn + 16 * j];
#pragma unroll
            for (int i = 0; i < 4; ++i)
#pragma unroll
                for (int j = 0; j < 4; ++j) acc[i][j] += am[i] * bn[j];
        }
        __syncthreads();
    }

    double (*red)[67] = Xs;   // reuse (past last sync)
#pragma unroll
    for (int i = 0; i < 4; ++i) {
        double m = -1e300;
#pragma unroll
        for (int j = 0; j < 4; ++j) {
            bool valid = (c0 + tn + 16 * j) < NCEN;
            double v = valid ? acc[i][j] : -1e300;
            m = fmax(m, v);
        }
        red[tn][tm + 16 * i] = m;
    }
    __syncthreads();
    if (tid < 64) {
        double m = red[0][tid];
#pragma unroll
        for (int g = 1; g < 16; ++g) m = fmax(m, red[g][tid]);
        pmax[(size_t)blockIdx.x * NTOK + t0 + tid] = m;
    }
}

// ------------------------------------------------------------------
// K2b: merged norm + cantor codes + histogram atomics. One wave per token.
// (8-ctile pmax reduce, matching simsgemm grid (8,32).)
__global__ __launch_bounds__(256) void codes3_k(const float* __restrict__ x,
                                                const double* __restrict__ pmax,
                                                const float* __restrict__ gwp,
                                                int* __restrict__ codes,
                                                int* __restrict__ hist) {
    int tid = threadIdx.x;
    int lane = tid & 63;
    int w = tid >> 6;
    int n = blockIdx.x * 4 + w;

    const float* xr = x + (size_t)n * DIM;
    double ss = 0.0;
#pragma unroll
    for (int i = 0; i < 8; ++i) {
        double v = (double)xr[lane + i * 64];
        ss += v * v;
    }
#pragma unroll
    for (int m = 32; m; m >>= 1) ss += __shfl_xor(ss, m);

    double m = (lane < 8) ? pmax[(size_t)lane * NTOK + n] : -1e300;
    m = fmax(m, __shfl_xor(m, 4));
    m = fmax(m, __shfl_xor(m, 2));
    m = fmax(m, __shfl_xor(m, 1));

    if (lane == 0) {
        double nrm = sqrt(ss) + 1e-12;
        double sims = m / nrm;
        double gwv = 1.0 / (1.0 + exp(-(double)gwp[0]));
        const double delta = 1.0 / 2047.0;
        double gd = 1.0 - sims;
        double pos = (n == NTOK - 1) ? 1.0 : (double)n * delta;
        double xc = pos * (1.0 - gwv) + gd * gwv;
        xc = fmin(fmax(xc, 1e-6), 1.0 - 1e-6);
        int code = 0;
#pragma unroll
        for (int l = 0; l < DEPTH; ++l) {
            double s3 = xc * 3.0;
            double dig = floor(s3);
            if (dig == 2.0) code |= 1 << (7 - l);
            xc = s3 - dig;
        }
        codes[n] = code;
        atomicAdd(&hist[(n >> 8) * 256 + code], 1);
    }
}

// ------------------------------------------------------------------
// K3: merged scan + stable scatter. 8 blocks x 256.
__global__ __launch_bounds__(256) void scanscatter_k(const int* __restrict__ hist,
                                                     const int* __restrict__ codes,
                                                     int* __restrict__ P,
                                                     int* __restrict__ bidx) {
    __shared__ int sc[256];
    __shared__ int cl[256];
    __shared__ int choff_l[256];
    int c = threadIdx.x;
    int b = blockIdx.x;
    int h[8];
    int t = 0;
#pragma unroll
    for (int g = 0; g < 8; ++g) { h[g] = hist[g * 256 + c]; t += h[g]; }
    sc[c] = t;
    __syncthreads();
    for (int off = 1; off < 256; off <<= 1) {
        int v = sc[c];
        int add = (c >= off) ? sc[c - off] : 0;
        __syncthreads();
        sc[c] = v + add;
        __syncthreads();
    }
    int incl = sc[c];
    int base = incl - t;
    if (b == 0) {
        P[c] = base;
        if (c == 255) P[256] = incl;   // == 2048
    }
    int pre = base;
    for (int g = 0; g < b; ++g) pre += h[g];
    choff_l[c] = pre;

    int idx = b * 256 + c;
    int myc = codes[idx];
    cl[c] = myc;
    __syncthreads();
    int rank = 0;
    for (int j = 0; j < c; ++j) rank += (cl[j] == myc) ? 1 : 0;
    bidx[choff_l[myc] + rank] = idx;
}

// ------------------------------------------------------------------
// K4: split-precision bf16x2 MFMA GEMM (proven R9/R10). C = A*B^T + bias.
__global__ __launch_bounds__(256) void gemm_mfma_k(const float* __restrict__ A,
                                                   const float* __restrict__ Bw,
                                                   const float* __restrict__ bias,
                                                   float* __restrict__ Cc,
                                                   int Nn) {
    __shared__ ushort Ahi[64][40], Alo[64][40];
    __shared__ ushort Bhi[64][40], Blo[64][40];
    int tid = threadIdx.x;
    int lane = tid & 63;
    int w = tid >> 6;
    int n0 = blockIdx.x * 64;
    int m0 = blockIdx.y * 64;
    int r = tid >> 2, q = tid & 3;
    int l15 = lane & 15, l4 = lane >> 4;

    f32x4 acc[4];
#pragma unroll
    for (int nt = 0; nt < 4; ++nt) acc[nt] = (f32x4){0.f, 0.f, 0.f, 0.f};

    for (int k0 = 0; k0 < 512; k0 += 32) {
        {
            const float* src = A + (size_t)(m0 + r) * 512 + k0 + q * 8;
            ushort h8[8], l8[8];
#pragma unroll
            for (int e = 0; e < 8; ++e) {
                float v = src[e];
                __hip_bfloat16 hb = __float2bfloat16(v);
                float hf = __bfloat162float(hb);
                __hip_bfloat16 lb = __float2bfloat16(v - hf);
                h8[e] = *reinterpret_cast<ushort*>(&hb);
                l8[e] = *reinterpret_cast<ushort*>(&lb);
            }
            *(uint4*)&Ahi[r][q * 8] = *(uint4*)h8;
            *(uint4*)&Alo[r][q * 8] = *(uint4*)l8;
        }
        {
            const float* src = Bw + (size_t)(n0 + r) * 512 + k0 + q * 8;
            ushort h8[8], l8[8];
#pragma unroll
            for (int e = 0; e < 8; ++e) {
                float v = src[e];
                __hip_bfloat16 hb = __float2bfloat16(v);
                float hf = __bfloat162float(hb);
                __hip_bfloat16 lb = __float2bfloat16(v - hf);
                h8[e] = *reinterpret_cast<ushort*>(&hb);
                l8[e] = *reinterpret_cast<ushort*>(&lb);
            }
            *(uint4*)&Bhi[r][q * 8] = *(uint4*)h8;
            *(uint4*)&Blo[r][q * 8] = *(uint4*)l8;
        }
        __syncthreads();

        bf16x8 ah = *(const bf16x8*)&Ahi[w * 16 + l15][l4 * 8];
        bf16x8 al = *(const bf16x8*)&Alo[w * 16 + l15][l4 * 8];
#pragma unroll
        for (int nt = 0; nt < 4; ++nt) {
            bf16x8 bh = *(const bf16x8*)&Bhi[nt * 16 + l15][l4 * 8];
            bf16x8 bl = *(const bf16x8*)&Blo[nt * 16 + l15][l4 * 8];
            acc[nt] = __builtin_amdgcn_mfma_f32_16x16x32_bf16(ah, bh, acc[nt], 0, 0, 0);
            acc[nt] = __builtin_amdgcn_mfma_f32_16x16x32_bf16(ah, bl, acc[nt], 0, 0, 0);
            acc[nt] = __builtin_amdgcn_mfma_f32_16x16x32_bf16(al, bh, acc[nt], 0, 0, 0);
        }
        __syncthreads();
    }

#pragma unroll
    for (int nt = 0; nt < 4; ++nt) {
        int col = n0 + nt * 16 + l15;
        float bv = bias[col];
#pragma unroll
        for (int rr = 0; rr < 4; ++rr) {
            int row = m0 + w * 16 + l4 * 4 + rr;
            Cc[(size_t)row * Nn + col] = acc[nt][rr] + bv;
        }
    }
}

// ------------------------------------------------------------------
// K5: attention with fused route selection (proven R10). 1 block = 1 query.
__global__ __launch_bounds__(256) void attn_v4(const float* __restrict__ qkv,
                                               const int* __restrict__ codes,
                                               const int* __restrict__ P,
                                               const int* __restrict__ bidx,
                                               float* __restrict__ Obuf) {
    __shared__ int rt[KWIN];
    __shared__ float sc[NHEAD][KWIN];
    __shared__ float part[4][DIM];
    int tid = threadIdx.x;
    int lane = tid & 63;
    int w = tid >> 6;

    int b = blockIdx.x;
    int ord = (b & 7) * 256 + (b >> 3);    // XCD-chunked, bijective on [0,2048)
    int q = bidx[ord];

    if (tid < 64) {
        int ci = codes[q];
        int dstar = -1;
        for (int r = 0; r < 4 && dstar < 0; ++r) {
            int d = r * 64 + lane;
            int loc = ci - d; if (loc < 0) loc = 0;
            int hic = ci + d; if (hic > 255) hic = 255;
            int cum = P[hic + 1] - P[loc];
            unsigned long long mb = __ballot(cum >= KWIN);
            if (mb) dstar = r * 64 + (int)__builtin_ctzll(mb);
        }
        int a = ci - dstar + 1; if (a < 0) a = 0;
        int bb = ci + dstar - 1; if (bb > 255) bb = 255;
        int inner = 0, baseA = 0;
        if (dstar > 0) { baseA = P[a]; inner = P[bb + 1] - baseA; }
        int rem = KWIN - inner;

        for (int t = lane; t < inner; t += 64) rt[t] = bidx[baseA + t];

        int lo = ci - dstar, hi = ci + dstar;
        int loS = 0, loL = 0, hiS = 0, hiL = 0;
        if (lo >= 0) { loS = P[lo]; loL = P[lo + 1] - loS; }
        if (dstar > 0 && hi <= 255) { hiS = P[hi]; hiL = P[hi + 1] - hiS; }

        int minI = rem - hiL; if (minI < 0) minI = 0;
        int maxI = (rem < loL) ? rem : loL;
        int ans = minI;
        int loI = minI, hiI = maxI;
        for (int it = 0; it < 12 && loI <= hiI; ++it) {
            int i = (loI + hiI) >> 1;
            int j = rem - i;
            bool tooMany = (i > 0 && j < hiL && bidx[loS + i - 1] > bidx[hiS + j]);
            bool tooFew  = (j > 0 && i < loL && bidx[hiS + j - 1] > bidx[loS + i]);
            if (tooMany) hiI = i - 1;
            else if (tooFew) loI = i + 1;
            else { ans = i; break; }
        }
        int ilo = ans;
        int jn = rem - ilo;
        for (int t = lane; t < ilo; t += 64) rt[inner + t] = bidx[loS + t];
        for (int t = lane; t < jn; t += 64) rt[inner + ilo + t] = bidx[hiS + t];
    }

    const float* qrow = qkv + (size_t)q * 1536 + lane * 8;
    float4 qa = *(const float4*)(qrow);
    float4 qb = *(const float4*)(qrow + 4);
    __syncthreads();

#pragma unroll 4
    for (int i = 0; i < 32; ++i) {
        int kk = w * 32 + i;
        int j = rt[kk];
        const float* kp = qkv + (size_t)j * 1536 + 512 + lane * 8;
        float4 k0 = *(const float4*)(kp);
        float4 k1 = *(const float4*)(kp + 4);
        float s = qa.x * k0.x + qa.y * k0.y + qa.z * k0.z + qa.w * k0.w
                + qb.x * k1.x + qb.y * k1.y + qb.z * k1.z + qb.w * k1.w;
        s += __shfl_xor(s, 1);
        s += __shfl_xor(s, 2);
        s += __shfl_xor(s, 4);
        if ((lane & 7) == 0) sc[lane >> 3][kk] = s * 0.125f;
    }
    __syncthreads();

    {
        int g = tid >> 5, l = tid & 31;
        float v0 = sc[g][l], v1 = sc[g][l + 32], v2 = sc[g][l + 64], v3 = sc[g][l + 96];
        float mx = fmaxf(fmaxf(v0, v1), fmaxf(v2, v3));
        for (int m = 16; m; m >>= 1) mx = fmaxf(mx, __shfl_xor(mx, m, 32));
        float e0 = expf(v0 - mx), e1 = expf(v1 - mx),
              e2 = expf(v2 - mx), e3 = expf(v3 - mx);
        float sum = e0 + e1 + e2 + e3;
        for (int m = 16; m; m >>= 1) sum += __shfl_xor(sum, m, 32);
        float inv = 1.f / sum;
        sc[g][l] = e0 * inv; sc[g][l + 32] = e1 * inv;
        sc[g][l + 64] = e2 * inv; sc[g][l + 96] = e3 * inv;
    }
    __syncthreads();

    float acc[8] = {0.f, 0.f, 0.f, 0.f, 0.f, 0.f, 0.f, 0.f};
    const float* sch = sc[lane >> 3];
#pragma unroll 4
    for (int i = 0; i < 32; ++i) {
        int kk = w * 32 + i;
        int j = rt[kk];
        float wgt = sch[kk];
        const float* vp = qkv + (size_t)j * 1536 + 1024 + lane * 8;
        float4 v0 = *(const float4*)(vp);
        float4 v1 = *(const float4*)(vp + 4);
        acc[0] += wgt * v0.x; acc[1] += wgt * v0.y;
        acc[2] += wgt * v0.z; acc[3] += wgt * v0.w;
        acc[4] += wgt * v1.x; acc[5] += wgt * v1.y;
        acc[6] += wgt * v1.z; acc[7] += wgt * v1.w;
    }
#pragma unroll
    for (int e = 0; e < 8; ++e) part[w][lane * 8 + e] = acc[e];
    __syncthreads();

#pragma unroll
    for (int r = 0; r < 2; ++r) {
        int d = r * 256 + tid;
        float o = part[0][d] + part[1][d] + part[2][d] + part[3][d];
        Obuf[(size_t)q * DIM + d] = o;
    }
}

// ------------------------------------------------------------------
extern "C" void kernel_launch(void* const* d_in, const int* in_sizes, int n_in,
                              void* d_out, int out_size, void* d_ws, size_t ws_size,
                              hipStream_t stream) {
    const float* x      = (const float*)d_in[0];
    const float* penta  = (const float*)d_in[1];
    const float* w_qkv  = (const float*)d_in[2];
    const float* b_qkv  = (const float*)d_in[3];
    const float* w_out  = (const float*)d_in[4];
    const float* b_out  = (const float*)d_in[5];
    const float* gw     = (const float*)d_in[6];
    float* out = (float*)d_out;
    char* ws = (char*)d_ws;

    double* cen   = (double*)(ws + 0);
    int* codes    = (int*)(ws + 2097152);
    int* P        = (int*)(ws + 2105344);
    int* bidx     = (int*)(ws + 2106400);
    double* pmax  = (double*)(ws + 2115584);   // [8][2048] f64
    int* hist     = (int*)(ws + 2377728);      // [8][256]
    float* qkv    = (float*)(ws + 3164160);
    float* Obuf   = (float*)(ws + 15747072);

    centroids_k<<<512, 256, 0, stream>>>(penta, cen, hist);
    simsgemm_k<<<dim3(8, 32), 256, 0, stream>>>(x, cen, pmax);
    codes3_k<<<512, 256, 0, stream>>>(x, pmax, gw, codes, hist);
    scanscatter_k<<<8, 256, 0, stream>>>(hist, codes, P, bidx);
    gemm_mfma_k<<<dim3(1536 / 64, 2048 / 64), 256, 0, stream>>>(x, w_qkv, b_qkv, qkv, 1536);
    attn_v4<<<NTOK, 256, 0, stream>>>(qkv, codes, P, bidx, Obuf);
    gemm_mfma_k<<<dim3(512 / 64, 2048 / 64), 256, 0, stream>>>(Obuf, w_out, b_out, out, 512);
}